// Round 4
// baseline (112.160 us; speedup 1.0000x reference)
//
#include <hip/hip_runtime.h>
#include <hip/hip_bf16.h>

typedef __attribute__((ext_vector_type(4))) float f32x4;

// ---------------- workspace layout (fp32 elements) ----------------
constexpr int WSF_PRE1 = 0;         // 512    attention query (conv3 out)
constexpr int WSF_LOGA = 512;       // 2048   attention logits
constexpr int WSF_ATTM = 2560;      // 128    per-block logit max
constexpr int WSF_ATTS = 2688;      // 128    per-block sum-exp
constexpr int WSF_PART = 2816;      // 32*1024 partial e*enc sums
constexpr int WSF_XT   = 35584;     // 5*512  xt chain
constexpr int WSF_GH   = 38144;     // 4*1536 precomputed Whh*h + bhh
constexpr int WSF_LOGV = 44288;     // 50257  vocab logits
constexpr int WSF_PM   = 94560;     // 786    per-block max
constexpr int WSF_PS   = 95360;     // 786    per-block sum-exp
constexpr int NVOCAB   = 50257;
constexpr int NBLK_V   = 786;       // ceil(50257/64)

__device__ __forceinline__ float wave_rsum(float v) {
#pragma unroll
    for (int o = 32; o > 0; o >>= 1) v += __shfl_down(v, o);
    return v; // lane 0 holds sum
}
__device__ __forceinline__ float sigm(float x) { return 1.0f / (1.0f + __expf(-x)); }

// =====================================================================
// K0: GRU hidden-side gates, all 4 layers (depends only on inputs).
// gh[l][r] = (Whh[l] @ h[l])[r] + bhh[l][r].  1536 blocks x 256, wave/row.
// =====================================================================
__global__ __launch_bounds__(256) void k_gruh(
    const float* __restrict__ whh, const float* __restrict__ bhh,
    const float* __restrict__ hstate, float* __restrict__ ws)
{
    const int tid = threadIdx.x, lane = tid & 63, wid = tid >> 6;
    const int R = blockIdx.x * 4 + wid;          // 0..6143
    const int l = R / 1536;
    const int r = R - l * 1536;
    const float* hp = hstate + l * 512;
    float h0[4], h1[4];
#pragma unroll
    for (int j = 0; j < 4; ++j) {
        h0[j] = hp[lane * 4 + j];
        h1[j] = hp[256 + lane * 4 + j];
    }
    const float* wr = whh + ((size_t)l * 1536 + r) * 512;
    f32x4 w0 = *reinterpret_cast<const f32x4*>(wr + lane * 4);
    f32x4 w1 = *reinterpret_cast<const f32x4*>(wr + 256 + lane * 4);
    float a = 0.f;
#pragma unroll
    for (int j = 0; j < 4; ++j) a += w0[j] * h0[j] + w1[j] * h1[j];
    a = wave_rsum(a);
    if (lane == 0) ws[WSF_GH + R] = a + bhh[l * 1536 + r];
}

// =====================================================================
// K1: pre-attention conv stack.  1 block x 512 threads (thread = position)
// =====================================================================
__global__ __launch_bounds__(512) void k_pre(
    const float* __restrict__ emb, const int* __restrict__ xidx,
    const float* __restrict__ hstate,
    const float* __restrict__ w1, const float* __restrict__ b1,
    const float* __restrict__ w2, const float* __restrict__ b2,
    const float* __restrict__ w3, const float* __restrict__ b3,
    const float* __restrict__ g1, const float* __restrict__ bb1,
    const float* __restrict__ g2, const float* __restrict__ bb2,
    const float* __restrict__ g3, const float* __restrict__ bb3,
    float* __restrict__ ws)
{
    constexpr int W1 = 0, B1 = 480, G1 = 512, BB1 = 544;
    constexpr int W2 = 576, B2 = 1056, G2 = 1061, BB2 = 1066;
    constexpr int W3 = 1071, B3 = 1086, G3 = 1087, BB3 = 1088, NW = 1089;
    __shared__ float s_w[NW];
    __shared__ float s_pre[5][512];
    __shared__ float s_y[32][512];
    __shared__ float s_stat[32][2];

    const int tid = threadIdx.x;
    const int lane = tid & 63, wid = tid >> 6;
    const int l = tid;

    if (tid < 480) s_w[W1 + tid] = w1[tid];
    if (tid < 32) { s_w[B1 + tid] = b1[tid]; s_w[G1 + tid] = g1[tid]; s_w[BB1 + tid] = bb1[tid]; }
    if (tid < 480) s_w[W2 + tid] = w2[tid];
    if (tid < 5) { s_w[B2 + tid] = b2[tid]; s_w[G2 + tid] = g2[tid]; s_w[BB2 + tid] = bb2[tid]; }
    if (tid < 15) s_w[W3 + tid] = w3[tid];
    if (tid == 0) { s_w[B3] = b3[0]; s_w[G3] = g3[0]; s_w[BB3] = bb3[0]; }

    const int x = xidx[0];
#pragma unroll
    for (int c = 0; c < 4; ++c) s_pre[c][l] = hstate[c * 512 + l];
    s_pre[4][l] = emb[(size_t)x * 512 + l];
    __syncthreads();

    // ---- conv1 (5->32) ----
    float px[5][3];
#pragma unroll
    for (int ic = 0; ic < 5; ++ic) {
        px[ic][0] = (l > 0)   ? s_pre[ic][l - 1] : 0.0f;
        px[ic][1] =             s_pre[ic][l];
        px[ic][2] = (l < 511) ? s_pre[ic][l + 1] : 0.0f;
    }
#pragma unroll 4
    for (int oc = 0; oc < 32; ++oc) {
        float a = s_w[B1 + oc];
#pragma unroll
        for (int ic = 0; ic < 5; ++ic)
#pragma unroll
            for (int k = 0; k < 3; ++k)
                a += s_w[W1 + oc * 15 + ic * 3 + k] * px[ic][k];
        s_y[oc][l] = a;
    }
    __syncthreads();

#pragma unroll
    for (int t = 0; t < 4; ++t) {
        const int oc = wid * 4 + t;
        float s = 0.f, s2 = 0.f;
#pragma unroll
        for (int j = 0; j < 8; ++j) {
            float v = s_y[oc][lane + j * 64];
            s += v; s2 += v * v;
        }
        s = wave_rsum(s); s2 = wave_rsum(s2);
        if (lane == 0) {
            float m = s * (1.0f / 512.0f);
            float var = s2 * (1.0f / 512.0f) - m * m;
            s_stat[oc][0] = m; s_stat[oc][1] = rsqrtf(var + 1e-5f);
        }
    }
    __syncthreads();
#pragma unroll 4
    for (int oc = 0; oc < 32; ++oc) {
        float m = s_stat[oc][0], r = s_stat[oc][1];
        s_y[oc][l] = fmaxf((s_y[oc][l] - m) * r * s_w[G1 + oc] + s_w[BB1 + oc], 0.0f);
    }
    __syncthreads();

    // ---- conv2 (32->5) + residual ----
    float y2[5];
#pragma unroll
    for (int oc = 0; oc < 5; ++oc) y2[oc] = s_w[B2 + oc];
#pragma unroll 2
    for (int ic = 0; ic < 32; ++ic) {
        float c0 = (l > 0)   ? s_y[ic][l - 1] : 0.0f;
        float c1 =             s_y[ic][l];
        float c2 = (l < 511) ? s_y[ic][l + 1] : 0.0f;
#pragma unroll
        for (int oc = 0; oc < 5; ++oc) {
            const int base = W2 + (oc * 32 + ic) * 3;
            y2[oc] += s_w[base] * c0 + s_w[base + 1] * c1 + s_w[base + 2] * c2;
        }
    }
#pragma unroll
    for (int oc = 0; oc < 5; ++oc) y2[oc] += s_pre[oc][l];
    __syncthreads();
#pragma unroll
    for (int oc = 0; oc < 5; ++oc) s_y[oc][l] = y2[oc];
    __syncthreads();

    if (wid < 5) {
        const int oc = wid;
        float s = 0.f, s2 = 0.f;
#pragma unroll
        for (int j = 0; j < 8; ++j) {
            float v = s_y[oc][lane + j * 64];
            s += v; s2 += v * v;
        }
        s = wave_rsum(s); s2 = wave_rsum(s2);
        if (lane == 0) {
            float m = s * (1.0f / 512.0f);
            float var = s2 * (1.0f / 512.0f) - m * m;
            s_stat[oc][0] = m; s_stat[oc][1] = rsqrtf(var + 1e-5f);
        }
    }
    __syncthreads();
#pragma unroll
    for (int oc = 0; oc < 5; ++oc) {
        float m = s_stat[oc][0], r = s_stat[oc][1];
        s_pre[oc][l] = fmaxf((y2[oc] - m) * r * s_w[G2 + oc] + s_w[BB2 + oc], 0.0f);
    }
    __syncthreads();

    // ---- conv3 (5->1) ----
    float a3 = s_w[B3];
#pragma unroll
    for (int ic = 0; ic < 5; ++ic) {
        float c0 = (l > 0)   ? s_pre[ic][l - 1] : 0.0f;
        float c1 =             s_pre[ic][l];
        float c2 = (l < 511) ? s_pre[ic][l + 1] : 0.0f;
        a3 += s_w[W3 + ic * 3] * c0 + s_w[W3 + ic * 3 + 1] * c1 + s_w[W3 + ic * 3 + 2] * c2;
    }
    s_y[0][l] = a3;
    __syncthreads();
    if (wid == 0) {
        float s = 0.f, s2 = 0.f;
#pragma unroll
        for (int j = 0; j < 8; ++j) {
            float v = s_y[0][lane + j * 64];
            s += v; s2 += v * v;
        }
        s = wave_rsum(s); s2 = wave_rsum(s2);
        if (lane == 0) {
            float m = s * (1.0f / 512.0f);
            float var = s2 * (1.0f / 512.0f) - m * m;
            s_stat[0][0] = m; s_stat[0][1] = rsqrtf(var + 1e-5f);
        }
    }
    __syncthreads();
    ws[WSF_PRE1 + l] = fmaxf((a3 - s_stat[0][0]) * s_stat[0][1] * s_w[G3] + s_w[BB3], 0.0f);
}

// =====================================================================
// K2a: attention logits + per-block (max, sum-exp).  128 blocks x 256
// =====================================================================
__global__ __launch_bounds__(256) void k_attlogit(
    const float* __restrict__ attw, const float* __restrict__ attb,
    float* __restrict__ ws)
{
    __shared__ float s_l[16];
    const int tid = threadIdx.x, lane = tid & 63, wid = tid >> 6;
    float q0[4], q1[4];
#pragma unroll
    for (int j = 0; j < 4; ++j) {
        q0[j] = ws[WSF_PRE1 + lane * 4 + j];
        q1[j] = ws[WSF_PRE1 + 256 + lane * 4 + j];
    }
    const int row0 = (blockIdx.x * 4 + wid) * 4;
#pragma unroll
    for (int r = 0; r < 4; ++r) {
        const int row = row0 + r;
        f32x4 w0 = *reinterpret_cast<const f32x4*>(attw + (size_t)row * 512 + lane * 4);
        f32x4 w1 = *reinterpret_cast<const f32x4*>(attw + (size_t)row * 512 + 256 + lane * 4);
        float a = 0.f;
#pragma unroll
        for (int j = 0; j < 4; ++j) a += w0[j] * q0[j] + w1[j] * q1[j];
        a = wave_rsum(a);
        if (lane == 0) {
            float v = a + attb[row];
            ws[WSF_LOGA + row] = v;
            s_l[wid * 4 + r] = v;
        }
    }
    __syncthreads();
    if (tid == 0) {
        float m = -INFINITY;
#pragma unroll
        for (int k = 0; k < 16; ++k) m = fmaxf(m, s_l[k]);
        float s = 0.f;
#pragma unroll
        for (int k = 0; k < 16; ++k) s += __expf(s_l[k] - m);
        ws[WSF_ATTM + blockIdx.x] = m;
        ws[WSF_ATTS + blockIdx.x] = s;
    }
}

// =====================================================================
// K2b: combine (m,s) partials + partial e*enc.  64 blocks x 256
// (32 j-chunks of 64 rows x 2 column halves)
// =====================================================================
__global__ __launch_bounds__(256) void k_attpv(
    const float* __restrict__ enc, float* __restrict__ ws)
{
    const int tid = threadIdx.x;
    // uniform deterministic combine of 128 (m,s) pairs
    float M = -INFINITY, S = 0.f;
    for (int i = 0; i < 128; ++i) {
        float mb = ws[WSF_ATTM + i], sb = ws[WSF_ATTS + i];
        if (mb > M) { S = S * __expf(M - mb) + sb; M = mb; }
        else        { S += sb * __expf(mb - M); }
    }
    const int jc = blockIdx.x >> 1, half = blockIdx.x & 1;
    __shared__ float s_e[64];
    if (tid < 64) s_e[tid] = __expf(ws[WSF_LOGA + jc * 64 + tid] - M);
    __syncthreads();

    const int col = half * 512 + tid * 2;
    const float* ep = enc + (size_t)(jc * 64) * 1024 + col;
    float a0 = 0.f, a1 = 0.f;
#pragma unroll 4
    for (int jj = 0; jj < 64; ++jj) {
        float2 e = *reinterpret_cast<const float2*>(ep + (size_t)jj * 1024);
        a0 += s_e[jj] * e.x;
        a1 += s_e[jj] * e.y;
    }
    ws[WSF_PART + jc * 1024 + col]     = a0;
    ws[WSF_PART + jc * 1024 + col + 1] = a1;
}

// =====================================================================
// K3: post-attention conv stack.  1 block x 512 threads
// =====================================================================
__global__ __launch_bounds__(512) void k_post(
    const float* __restrict__ emb, const int* __restrict__ xidx,
    const float* __restrict__ w4, const float* __restrict__ b4,
    const float* __restrict__ w5, const float* __restrict__ b5,
    const float* __restrict__ w6, const float* __restrict__ b6,
    const float* __restrict__ g4, const float* __restrict__ bb4,
    const float* __restrict__ g5, const float* __restrict__ bb5,
    const float* __restrict__ g6, const float* __restrict__ bb6,
    float* __restrict__ ws)
{
    constexpr int W4 = 0, B4 = 288, G4 = 320, BB4 = 352;
    constexpr int W5 = 384, B5 = 672, G5 = 675, BB5 = 678;
    constexpr int W6 = 681, B6 = 690, G6 = 691, BB6 = 692, NW = 693;
    __shared__ float s_w[NW];
    __shared__ float s_com[3][512];
    __shared__ float s_y[32][512];
    __shared__ float s_stat[32][2];

    const int tid = threadIdx.x;
    const int lane = tid & 63, wid = tid >> 6;
    const int l = tid;

    if (tid < 288) s_w[W4 + tid] = w4[tid];
    if (tid < 32) { s_w[B4 + tid] = b4[tid]; s_w[G4 + tid] = g4[tid]; s_w[BB4 + tid] = bb4[tid]; }
    if (tid < 288) s_w[W5 + tid] = w5[tid];
    if (tid < 3) { s_w[B5 + tid] = b5[tid]; s_w[G5 + tid] = g5[tid]; s_w[BB5 + tid] = bb5[tid]; }
    if (tid < 9) s_w[W6 + tid] = w6[tid];
    if (tid == 0) { s_w[B6] = b6[0]; s_w[G6] = g6[0]; s_w[BB6] = bb6[0]; }

    // combine attention (m,s) partials -> S (deterministic, same order as k_attpv)
    float M = -INFINITY, S = 0.f;
    for (int i = 0; i < 128; ++i) {
        float mb = ws[WSF_ATTM + i], sb = ws[WSF_ATTS + i];
        if (mb > M) { S = S * __expf(M - mb) + sb; M = mb; }
        else        { S += sb * __expf(mb - M); }
    }
    const float invS = 1.0f / S;
    float a0 = 0.f, a1 = 0.f;
#pragma unroll 8
    for (int p = 0; p < 32; ++p) {
        a0 += ws[WSF_PART + p * 1024 + l];
        a1 += ws[WSF_PART + p * 1024 + 512 + l];
    }
    const int x = xidx[0];
    s_com[0][l] = a0 * invS;
    s_com[1][l] = a1 * invS;
    s_com[2][l] = emb[(size_t)x * 512 + l];
    __syncthreads();

    // ---- conv4 (3->32) ----
    float px[3][3];
#pragma unroll
    for (int ic = 0; ic < 3; ++ic) {
        px[ic][0] = (l > 0)   ? s_com[ic][l - 1] : 0.0f;
        px[ic][1] =             s_com[ic][l];
        px[ic][2] = (l < 511) ? s_com[ic][l + 1] : 0.0f;
    }
#pragma unroll 4
    for (int oc = 0; oc < 32; ++oc) {
        float a = s_w[B4 + oc];
#pragma unroll
        for (int ic = 0; ic < 3; ++ic)
#pragma unroll
            for (int k = 0; k < 3; ++k)
                a += s_w[W4 + oc * 9 + ic * 3 + k] * px[ic][k];
        s_y[oc][l] = a;
    }
    __syncthreads();

#pragma unroll
    for (int t = 0; t < 4; ++t) {
        const int oc = wid * 4 + t;
        float s = 0.f, s2 = 0.f;
#pragma unroll
        for (int j = 0; j < 8; ++j) {
            float v = s_y[oc][lane + j * 64];
            s += v; s2 += v * v;
        }
        s = wave_rsum(s); s2 = wave_rsum(s2);
        if (lane == 0) {
            float m = s * (1.0f / 512.0f);
            float var = s2 * (1.0f / 512.0f) - m * m;
            s_stat[oc][0] = m; s_stat[oc][1] = rsqrtf(var + 1e-5f);
        }
    }
    __syncthreads();
#pragma unroll 4
    for (int oc = 0; oc < 32; ++oc) {
        float m = s_stat[oc][0], r = s_stat[oc][1];
        s_y[oc][l] = fmaxf((s_y[oc][l] - m) * r * s_w[G4 + oc] + s_w[BB4 + oc], 0.0f);
    }
    __syncthreads();

    // ---- conv5 (32->3) + residual ----
    float y2[3];
#pragma unroll
    for (int oc = 0; oc < 3; ++oc) y2[oc] = s_w[B5 + oc];
#pragma unroll 2
    for (int ic = 0; ic < 32; ++ic) {
        float c0 = (l > 0)   ? s_y[ic][l - 1] : 0.0f;
        float c1 =             s_y[ic][l];
        float c2 = (l < 511) ? s_y[ic][l + 1] : 0.0f;
#pragma unroll
        for (int oc = 0; oc < 3; ++oc) {
            const int base = W5 + (oc * 32 + ic) * 3;
            y2[oc] += s_w[base] * c0 + s_w[base + 1] * c1 + s_w[base + 2] * c2;
        }
    }
#pragma unroll
    for (int oc = 0; oc < 3; ++oc) y2[oc] += s_com[oc][l];
    __syncthreads();
#pragma unroll
    for (int oc = 0; oc < 3; ++oc) s_y[oc][l] = y2[oc];
    __syncthreads();
    if (wid < 3) {
        const int oc = wid;
        float s = 0.f, s2 = 0.f;
#pragma unroll
        for (int j = 0; j < 8; ++j) {
            float v = s_y[oc][lane + j * 64];
            s += v; s2 += v * v;
        }
        s = wave_rsum(s); s2 = wave_rsum(s2);
        if (lane == 0) {
            float m = s * (1.0f / 512.0f);
            float var = s2 * (1.0f / 512.0f) - m * m;
            s_stat[oc][0] = m; s_stat[oc][1] = rsqrtf(var + 1e-5f);
        }
    }
    __syncthreads();
#pragma unroll
    for (int oc = 0; oc < 3; ++oc) {
        float m = s_stat[oc][0], r = s_stat[oc][1];
        s_com[oc][l] = fmaxf((y2[oc] - m) * r * s_w[G5 + oc] + s_w[BB5 + oc], 0.0f);
    }
    __syncthreads();

    // ---- conv6 (3->1) ----
    float a6 = s_w[B6];
#pragma unroll
    for (int ic = 0; ic < 3; ++ic) {
        float c0 = (l > 0)   ? s_com[ic][l - 1] : 0.0f;
        float c1 =             s_com[ic][l];
        float c2 = (l < 511) ? s_com[ic][l + 1] : 0.0f;
        a6 += s_w[W6 + ic * 3] * c0 + s_w[W6 + ic * 3 + 1] * c1 + s_w[W6 + ic * 3 + 2] * c2;
    }
    s_y[0][l] = a6;
    __syncthreads();
    if (wid == 0) {
        float s = 0.f, s2 = 0.f;
#pragma unroll
        for (int j = 0; j < 8; ++j) {
            float v = s_y[0][lane + j * 64];
            s += v; s2 += v * v;
        }
        s = wave_rsum(s); s2 = wave_rsum(s2);
        if (lane == 0) {
            float m = s * (1.0f / 512.0f);
            float var = s2 * (1.0f / 512.0f) - m * m;
            s_stat[0][0] = m; s_stat[0][1] = rsqrtf(var + 1e-5f);
        }
    }
    __syncthreads();
    ws[WSF_XT + l] = fmaxf((a6 - s_stat[0][0]) * s_stat[0][1] * s_w[G6] + s_w[BB6], 0.0f);
}

// =====================================================================
// K4: GRU input-side gates + cell update, one layer.  128 blocks x 256.
// Block owns 4 units; wave w computes unit's 3 gate rows (Wih only);
// hidden-side gates come precomputed from k_gruh.
// =====================================================================
__global__ __launch_bounds__(256) void k_grux(
    const float* __restrict__ wih, const float* __restrict__ bih,
    const float* __restrict__ hstate,
    const float* __restrict__ xt_in, float* __restrict__ xt_out,
    float* __restrict__ hout, const float* __restrict__ gh, int layer)
{
    wih += (size_t)layer * 1536 * 512;
    bih += layer * 1536;
    const float* hp = hstate + layer * 512;

    const int tid = threadIdx.x, lane = tid & 63, wid = tid >> 6;
    float xq0[4], xq1[4];
#pragma unroll
    for (int j = 0; j < 4; ++j) {
        xq0[j] = xt_in[lane * 4 + j];
        xq1[j] = xt_in[256 + lane * 4 + j];
    }
    __shared__ float s_g[4][3];
    const int u = blockIdx.x * 4 + wid;   // unit 0..511
#pragma unroll
    for (int g = 0; g < 3; ++g) {
        const float* wr = wih + (size_t)(u + g * 512) * 512;
        f32x4 w0 = *reinterpret_cast<const f32x4*>(wr + lane * 4);
        f32x4 w1 = *reinterpret_cast<const f32x4*>(wr + 256 + lane * 4);
        float a = 0.f;
#pragma unroll
        for (int j = 0; j < 4; ++j) a += w0[j] * xq0[j] + w1[j] * xq1[j];
        a = wave_rsum(a);
        if (lane == 0) s_g[wid][g] = a + bih[u + g * 512];
    }
    __syncthreads();
    if (tid < 4) {
        const int i = blockIdx.x * 4 + tid;
        float r = sigm(s_g[tid][0] + gh[i]);
        float z = sigm(s_g[tid][1] + gh[i + 512]);
        float n = tanhf(s_g[tid][2] + r * gh[i + 1024]);
        float h = (1.0f - z) * n + z * hp[i];
        xt_out[i] = h;
        hout[i] = h;
    }
}

// =====================================================================
// K5: vocab GEMV + per-block online (max, sum-exp).  786 blocks x 256
// =====================================================================
__global__ __launch_bounds__(256) void k_vocab(
    const float* __restrict__ low, const float* __restrict__ lob,
    float* __restrict__ ws)
{
    const int tid = threadIdx.x, lane = tid & 63, wid = tid >> 6;
    float q0[4], q1[4];
#pragma unroll
    for (int j = 0; j < 4; ++j) {
        q0[j] = ws[WSF_XT + 4 * 512 + lane * 4 + j];
        q1[j] = ws[WSF_XT + 4 * 512 + 256 + lane * 4 + j];
    }

    const int row0 = blockIdx.x * 64 + wid * 16;
    float m = -INFINITY, s = 0.0f;
#pragma unroll 4
    for (int r = 0; r < 16; ++r) {
        const int row = row0 + r;
        if (row < NVOCAB) {
            f32x4 w0 = *reinterpret_cast<const f32x4*>(low + (size_t)row * 512 + lane * 4);
            f32x4 w1 = *reinterpret_cast<const f32x4*>(low + (size_t)row * 512 + 256 + lane * 4);
            float a = 0.f;
#pragma unroll
            for (int j = 0; j < 4; ++j) a += w0[j] * q0[j] + w1[j] * q1[j];
            a = wave_rsum(a);
            if (lane == 0) {
                float v = a + lob[row];
                ws[WSF_LOGV + row] = v;
                if (v > m) { s = s * __expf(m - v) + 1.0f; m = v; }
                else       { s += __expf(v - m); }
            }
        }
    }
    __shared__ float sm[4], ss[4];
    if (lane == 0) { sm[wid] = m; ss[wid] = s; }
    __syncthreads();
    if (tid == 0) {
        float M = -INFINITY, S = 0.0f;
#pragma unroll
        for (int w = 0; w < 4; ++w) {
            float mb = sm[w], sb = ss[w];
            if (sb > 0.0f) {
                if (mb > M) { S = S * __expf(M - mb) + sb; M = mb; }
                else        { S += sb * __expf(mb - M); }
            }
        }
        ws[WSF_PM + blockIdx.x] = M;
        ws[WSF_PS + blockIdx.x] = S;
    }
}

// =====================================================================
// K6: per-block redundant LSE combine (deterministic) + write log-probs.
// 197 blocks x 256.
// =====================================================================
__global__ __launch_bounds__(256) void k_outlse(
    const float* __restrict__ ws, float* __restrict__ out)
{
    __shared__ float sm[256], ss[256];
    const int tid = threadIdx.x;
    float M = -INFINITY, S = 0.0f;
    for (int i = tid; i < NBLK_V; i += 256) {
        float mb = ws[WSF_PM + i], sb = ws[WSF_PS + i];
        if (mb > M) { S = S * __expf(M - mb) + sb; M = mb; }
        else        { S += sb * __expf(mb - M); }
    }
    sm[tid] = M; ss[tid] = S;
    __syncthreads();
    for (int st = 128; st > 0; st >>= 1) {
        if (tid < st) {
            float mb = sm[tid + st], sb = ss[tid + st];
            if (sb > 0.0f) {
                if (mb > sm[tid]) { ss[tid] = ss[tid] * __expf(sm[tid] - mb) + sb; sm[tid] = mb; }
                else              { ss[tid] += sb * __expf(mb - sm[tid]); }
            }
        }
        __syncthreads();
    }
    const float lse = sm[0] + logf(ss[0]);
    const int i = blockIdx.x * 256 + tid;
    if (i < NVOCAB) out[i] = ws[WSF_LOGV + i] - lse;
}

// =====================================================================
extern "C" void kernel_launch(void* const* d_in, const int* in_sizes, int n_in,
                              void* d_out, int out_size, void* d_ws, size_t ws_size,
                              hipStream_t stream)
{
    (void)in_sizes; (void)n_in; (void)out_size; (void)ws_size;
    const float* emb     = (const float*)d_in[0];
    const float* conv1_w = (const float*)d_in[1];  const float* conv1_b = (const float*)d_in[2];
    const float* conv2_w = (const float*)d_in[3];  const float* conv2_b = (const float*)d_in[4];
    const float* conv3_w = (const float*)d_in[5];  const float* conv3_b = (const float*)d_in[6];
    const float* conv4_w = (const float*)d_in[7];  const float* conv4_b = (const float*)d_in[8];
    const float* conv5_w = (const float*)d_in[9];  const float* conv5_b = (const float*)d_in[10];
    const float* conv6_w = (const float*)d_in[11]; const float* conv6_b = (const float*)d_in[12];
    const float* bn1_g = (const float*)d_in[13];   const float* bn1_b = (const float*)d_in[14];
    const float* bn2_g = (const float*)d_in[15];   const float* bn2_b = (const float*)d_in[16];
    const float* bn3_g = (const float*)d_in[17];   const float* bn3_b = (const float*)d_in[18];
    const float* bn4_g = (const float*)d_in[19];   const float* bn4_b = (const float*)d_in[20];
    const float* bn5_g = (const float*)d_in[21];   const float* bn5_b = (const float*)d_in[22];
    const float* bn6_g = (const float*)d_in[23];   const float* bn6_b = (const float*)d_in[24];
    const float* att_w = (const float*)d_in[25];   const float* att_b = (const float*)d_in[26];
    const float* gru_wih = (const float*)d_in[27]; const float* gru_whh = (const float*)d_in[28];
    const float* gru_bih = (const float*)d_in[29]; const float* gru_bhh = (const float*)d_in[30];
    const float* lo_w = (const float*)d_in[31];    const float* lo_b = (const float*)d_in[32];
    const float* h_state = (const float*)d_in[33];
    const float* enc = (const float*)d_in[34];
    const int* x = (const int*)d_in[35];

    float* ws = (float*)d_ws;
    float* out = (float*)d_out;

    k_gruh<<<1536, 256, 0, stream>>>(gru_whh, gru_bhh, h_state, ws);
    k_pre<<<1, 512, 0, stream>>>(emb, x, h_state,
        conv1_w, conv1_b, conv2_w, conv2_b, conv3_w, conv3_b,
        bn1_g, bn1_b, bn2_g, bn2_b, bn3_g, bn3_b, ws);
    k_attlogit<<<128, 256, 0, stream>>>(att_w, att_b, ws);
    k_attpv<<<64, 256, 0, stream>>>(enc, ws);
    k_post<<<1, 512, 0, stream>>>(emb, x,
        conv4_w, conv4_b, conv5_w, conv5_b, conv6_w, conv6_b,
        bn4_g, bn4_b, bn5_g, bn5_b, bn6_g, bn6_b, ws);
    for (int l = 0; l < 4; ++l) {
        k_grux<<<128, 256, 0, stream>>>(gru_wih, gru_bih, h_state,
            ws + WSF_XT + l * 512, ws + WSF_XT + (l + 1) * 512,
            out + NVOCAB + l * 512, ws + WSF_GH + l * 1536, l);
    }
    k_vocab<<<NBLK_V, 256, 0, stream>>>(lo_w, lo_b, ws);
    k_outlse<<<197, 256, 0, stream>>>(ws, out);
}